// Round 18
// baseline (189.370 us; speedup 1.0000x reference)
//
#include <hip/hip_runtime.h>
#include <hip/hip_bf16.h>
#include <stdint.h>

// ---- constants ----
// B=8, Cin=128, H=W=160, Ce=64, NH=4, HC=16, N=80, Cg=512, Co=128
// P2: bf16, cs-major planes [4 cs][8 b][162][176][32 ci]
//     interior (h,w) -> (h+1, w+8); borders zero.
// k_mega (R18 = R17 phase-split + 4Mx1N conv): Phase 1 embed+scores
//   (R17-verified). Phase 2 conv with wave = 1 h-row x 64 co:
//   2 ds_read -> 8 MFMA per wave-tap (LDS work halves, 36->18 us/CU).
//   Registers fit now that accE/BE left the loop (R13's spill cause):
//   acc 32 AGPR + Bb[2][4] 32 + A[2] 8 + addr ~20 < 84-VGPR cap @(256,3).
// Spill tripwire: WRITE must stay 102.4 MB.

typedef __attribute__((ext_vector_type(8))) short short8;
typedef __attribute__((ext_vector_type(4))) float f32x4;

#define PCH2 ((size_t)8 * 162 * 176 * 32)   // elements per cs-plane

#define GLDS(gp, lp) __builtin_amdgcn_global_load_lds(                         \
    (const __attribute__((address_space(1))) void*)(gp),                       \
    (__attribute__((address_space(3))) void*)(lp), 16, 0, 0)

__device__ __forceinline__ unsigned short f2bf(float f) {
  unsigned int u = __float_as_uint(f);
  u += 0x7fff + ((u >> 16) & 1);   // round-to-nearest-even
  return (unsigned short)(u >> 16);
}

// ------------------------------------------------------------------
// P0: x fp32 NCHW -> bf16 cs-major padded planes, zero borders.
// ------------------------------------------------------------------
__global__ __launch_bounds__(256) void k_prep_x(const float* __restrict__ x,
                                                unsigned short* __restrict__ P2) {
  __shared__ unsigned short T[8192];   // 16 KB
  int b = blockIdx.x / 112, blk = blockIdx.x % 112;
  int tid = threadIdx.x;
  int px = blk * 256 + tid;            // read-phase px (one per thread)
  int hp = px / 176, wp = px - hp * 176;
  bool interior = (px < 28512) && (hp >= 1) && (hp <= 160) && (wp >= 8) && (wp < 168);
  const float* xb = x + (size_t)b * 128 * 25600 + (hp - 1) * 160 + (wp - 8);
  int q = tid >> 2, os = tid & 3;      // store-phase (px-group, chunk)

  for (int cs = 0; cs < 4; ++cs) {
    short8 v[4];
#pragma unroll
    for (int s = 0; s < 4; ++s) {
#pragma unroll
      for (int j = 0; j < 8; ++j) {
        float f = interior ? xb[(size_t)(cs * 32 + s * 8 + j) * 25600] : 0.f;
        v[s][j] = (short)f2bf(f);
      }
    }
    if (cs) __syncthreads();           // prior store-phase reads done
#pragma unroll
    for (int s = 0; s < 4; ++s)
      *(short8*)(&T[(tid * 4 + (s ^ (tid & 3))) * 8]) = v[s];
    __syncthreads();
#pragma unroll
    for (int ph = 0; ph < 4; ++ph) {
      int lpx = ph * 64 + q;
      int opx = blk * 256 + lpx;
      if (opx < 28512) {
        int ohp = opx / 176, owp = opx - ohp * 176;
        size_t obase = (((size_t)b * 162 + ohp) * 176 + owp) * 32 + os * 8;
        short8 w = *(const short8*)(&T[(lpx * 4 + (os ^ (lpx & 3))) * 8]);
        *(short8*)(&P2[(size_t)cs * PCH2 + obase]) = w;
      }
    }
  }
}

// ------------------------------------------------------------------
// P1: weight conversions + BN2 folding
// ------------------------------------------------------------------
__global__ __launch_bounds__(256) void k_prep_misc(
    const float* __restrict__ w_embed, const float* __restrict__ w_proj,
    const float* __restrict__ g2, const float* __restrict__ b2,
    const float* __restrict__ rm2, const float* __restrict__ rv2,
    unsigned short* __restrict__ W1t, unsigned short* __restrict__ Wpt,
    float* __restrict__ s2, float* __restrict__ t2) {
  int idx = blockIdx.x * 256 + threadIdx.x;
  if (idx < 8192) { W1t[idx] = f2bf(w_embed[idx]); return; }
  idx -= 8192;
  if (idx < 147456) {
    int cs = idx / 36864, r = idx - cs * 36864;
    int tap = r >> 12, r2 = r & 4095;
    int co = r2 >> 5, ci5 = r2 & 31;
    int ci = cs * 32 + ci5;
    Wpt[idx] = f2bf(w_proj[(co * 128 + ci) * 9 + tap]);
    return;
  }
  idx -= 147456;
  if (idx < 128) {
    float s = g2[idx] * rsqrtf(rv2[idx] + 1e-3f);
    s2[idx] = s;
    t2[idx] = b2[idx] - rm2[idx] * s;
  }
}

// ------------------------------------------------------------------
// P2k: guide GEMM + BN1 folding
// ------------------------------------------------------------------
__global__ __launch_bounds__(64) void k_guide(
    const float* __restrict__ guide, const float* __restrict__ Wg,
    const float* __restrict__ bg, const float* __restrict__ g1,
    const float* __restrict__ b1, const float* __restrict__ rm1,
    const float* __restrict__ rv1, unsigned short* __restrict__ Gpad,
    float* __restrict__ Cst) {
  int b = blockIdx.x / 80, n = blockIdx.x % 80;
  __shared__ float gs[512];
  const float* gr = guide + ((size_t)b * 80 + n) * 512;
  for (int i = threadIdx.x; i < 512; i += 64) gs[i] = gr[i];
  __syncthreads();
  int ce = threadIdx.x;
  const float* wr = Wg + (size_t)ce * 512;
  float acc = 0.f;
  for (int k = 0; k < 512; k += 4)
    acc += gs[k] * wr[k] + gs[k + 1] * wr[k + 1] + gs[k + 2] * wr[k + 2] +
           gs[k + 3] * wr[k + 3];
  float raw = acc + bg[ce];
  float s1 = g1[ce] * rsqrtf(rv1[ce] + 1e-3f);
  float t1 = b1[ce] - rm1[ce] * s1;
  int head = ce >> 4, c = ce & 15;
  size_t gp = (((size_t)b * 4 + head) * 80 + n) * 32;
  Gpad[gp + c] = f2bf(raw * s1);
  Gpad[gp + 16 + c] = 0;
  float cp = raw * t1;
  cp += __shfl_xor(cp, 1);
  cp += __shfl_xor(cp, 2);
  cp += __shfl_xor(cp, 4);
  cp += __shfl_xor(cp, 8);
  if (c == 0) Cst[((size_t)b * 4 + head) * 80 + n] = cp;
}

// ------------------------------------------------------------------
// K: fused conv+attn, co-split blocks, phase-split, 4Mx1N conv waves.
// Block = [4h x 32w px] x [64 co], 3200 blocks, 4 waves.
// LDS: XA 2x15,360 + AWL [4][64] f32 = 31,744 B -> 4 blocks/CU by LDS.
// Phase 1 (waves 2Mx2N): embed compact staging + scores -> AWL.
// Phase 2 (waves = 1 h-row x 64 co): conv, 2 ds_read -> 8 MFMA/tap.
// ------------------------------------------------------------------
__global__ __launch_bounds__(256, 3) void k_mega(
    const unsigned short* __restrict__ P2, const unsigned short* __restrict__ W1t,
    const unsigned short* __restrict__ Wpt, const unsigned short* __restrict__ Gpad,
    const float* __restrict__ Cst, const float* __restrict__ attn_bias,
    const float* __restrict__ s2, const float* __restrict__ t2,
    float* __restrict__ out) {
  __shared__ unsigned short XA[2][7680];
  __shared__ float AWL[4][64];
  int b = blockIdx.x & 7;
  int r = blockIdx.x >> 3;          // 0..399
  int blkN = r & 1;                 // co-half / head-pair select
  int tile = r >> 1;                // 0..199
  int ht = tile / 5, wt = tile - ht * 5;
  int h0 = ht * 4, w0 = wt * 32;
  int tid = threadIdx.x, lane = tid & 63, wv = tid >> 6;
  int l15 = lane & 15, l4 = lane >> 4;
  int mh = wv >> 1, nh = wv & 1;

  // ================= PHASE 1: embed + scores -> AWL (R17-verified) =========
  {
    int a2off[2];
#pragma unroll
    for (int k = 0; k < 2; ++k) {
      int c = (wv * 2 + k) * 64 + lane;   // 0..511
      int rr2 = c >> 7, rem = c & 127;
      int p = rem >> 2, sp = rem & 3;
      int s = sp ^ ((p >> 1) & 3);
      a2off[k] = (int)(((b * 162 + h0 + 1 + rr2) * 176 + (w0 + 8 + p)) * 32 + s * 8);
    }
    int a2base[4];
#pragma unroll
    for (int j = 0; j < 4; ++j) {
      int rr2 = mh * 2 + (j >> 1);
      int p = (j & 1) * 16 + l15;
      a2base[j] = rr2 * 128 + p * 4 + (l4 ^ ((p >> 1) & 3));
    }

    f32x4 accE[4];
#pragma unroll
    for (int j = 0; j < 4; ++j) accE[j] = (f32x4){0.f, 0.f, 0.f, 0.f};

#pragma unroll
    for (int k = 0; k < 2; ++k)
      GLDS(P2 + a2off[k], &XA[0][(wv * 2 + k) * 512]);
    __syncthreads();

#pragma unroll
    for (int cs = 0; cs < 4; ++cs) {
      if (cs < 3) {
#pragma unroll
        for (int k = 0; k < 2; ++k)
          GLDS(P2 + (size_t)(cs + 1) * PCH2 + a2off[k],
               &XA[(cs + 1) & 1][(wv * 2 + k) * 512]);
      }
      short8 BE = *(const short8*)(W1t + (blkN * 32 + nh * 16 + l15) * 128 +
                                   cs * 32 + l4 * 8);
      short8 A2[4];
#pragma unroll
      for (int j = 0; j < 4; ++j)
        A2[j] = *(const short8*)(&XA[cs & 1][a2base[j] * 8]);
#pragma unroll
      for (int j = 0; j < 4; ++j)
        accE[j] = __builtin_amdgcn_mfma_f32_16x16x32_bf16(A2[j], BE, accE[j], 0, 0, 0);
      __syncthreads();
    }

    // E: wave-private [64 px][2 chunks][8] bf16 at element offset wv*1024
    unsigned short* Eb = &XA[0][0];
#pragma unroll
    for (int j = 0; j < 4; ++j)
#pragma unroll
      for (int rr = 0; rr < 4; ++rr) {
        int pxl = (j >> 1) * 32 + (j & 1) * 16 + l4 * 4 + rr;
        int chunk = (l15 >> 3) ^ (pxl & 1);
        Eb[wv * 1024 + pxl * 16 + chunk * 8 + (l15 & 7)] = f2bf(accE[j][rr]);
      }

    const f32x4 zf = (f32x4){0.f, 0.f, 0.f, 0.f};
    int head = blkN * 2 + nh;
    short8 Ga[5];
    f32x4 cst[5];
#pragma unroll
    for (int m5 = 0; m5 < 5; ++m5) {
      Ga[m5] = *(const short8*)(Gpad + (((size_t)b * 4 + head) * 80 + m5 * 16 + l15) * 32 + l4 * 8);
      cst[m5] = *(const f32x4*)(Cst + ((size_t)b * 4 + head) * 80 + m5 * 16 + l4 * 4);
    }
    float bias = attn_bias[head];
#pragma unroll
    for (int nt = 0; nt < 4; ++nt) {
      int pxl = nt * 16 + l15;
      int chr = (l4 & 1) ^ (pxl & 1);   // l4>=2 rereads: garbage x Gpad-zeros = 0
      short8 Bf = *(const short8*)(&Eb[wv * 1024 + pxl * 16 + chr * 8]);
      float mx = -3.0e38f;
#pragma unroll
      for (int m5 = 0; m5 < 5; ++m5) {
        f32x4 sc = __builtin_amdgcn_mfma_f32_16x16x32_bf16(Ga[m5], Bf, zf, 0, 0, 0);
#pragma unroll
        for (int rr = 0; rr < 4; ++rr) mx = fmaxf(mx, sc[rr] + cst[m5][rr]);
      }
      mx = fmaxf(mx, __shfl_xor(mx, 16));
      mx = fmaxf(mx, __shfl_xor(mx, 32));
      if (lane < 16) AWL[wv][nt * 16 + lane] = 1.f / (1.f + __expf(-(mx * 0.25f + bias)));
    }
  }
  __syncthreads();   // E/AWL visible block-wide; XA free for conv staging

  // ================= PHASE 2: 3x3 conv, wave = h-row x 64 co ==============
  size_t aoff[4];
#pragma unroll
  for (int k = 0; k < 4; ++k) {
    int i = wv * 4 + k;
    int c = i * 64 + lane;
    int cc = (c < 960) ? c : 0;
    int row = cc / 160, rem = cc - row * 160;
    int px = rem >> 2, sp = rem & 3;
    int s = sp ^ ((px >> 1) & 3);
    aoff[k] = (((size_t)b * 162 + h0 + row) * 176 + (w0 + 7 + px)) * 32 + s * 8;
  }
  int abase[2][3];
#pragma unroll
  for (int wh = 0; wh < 2; ++wh)
#pragma unroll
    for (int kx = 0; kx < 3; ++kx) {
      int px = wh * 16 + l15 + kx;
      abase[wh][kx] = px * 4 + (l4 ^ ((px >> 1) & 3));
    }
  // B-frag global offsets: full 64-co half per wave (waves share lines -> L1)
  int boff[4];
#pragma unroll
  for (int nt = 0; nt < 4; ++nt)
    boff[nt] = (blkN * 64 + nt * 16 + l15) * 32 + l4 * 8;

  f32x4 acc[2][4];
#pragma unroll
  for (int wh = 0; wh < 2; ++wh)
#pragma unroll
    for (int nt = 0; nt < 4; ++nt) acc[wh][nt] = (f32x4){0.f, 0.f, 0.f, 0.f};

  // prologue: async-stage A(cs=0); init B depth-1 pipeline (2 slots)
#pragma unroll
  for (int k = 0; k < 4; ++k) {
    int i = wv * 4 + k;
    if (i < 15) GLDS(P2 + aoff[k], &XA[0][i * 512]);
  }
  short8 Bb[2][4];
#pragma unroll
  for (int nt = 0; nt < 4; ++nt)
    Bb[0][nt] = *(const short8*)(Wpt + boff[nt]);
  __syncthreads();

#pragma unroll
  for (int cs = 0; cs < 4; ++cs) {
    if (cs < 3) {
#pragma unroll
      for (int k = 0; k < 4; ++k) {
        int i = wv * 4 + k;
        if (i < 15)
          GLDS(P2 + (size_t)(cs + 1) * PCH2 + aoff[k], &XA[(cs + 1) & 1][i * 512]);
      }
    }
#pragma unroll
    for (int tap = 0; tap < 9; ++tap) {
      const int t = cs * 9 + tap;
      // prefetch B slab t+1 into the other slot
      if (t + 1 < 36) {
#pragma unroll
        for (int nt = 0; nt < 4; ++nt)
          Bb[(t + 1) & 1][nt] =
              *(const short8*)(Wpt + (size_t)(t + 1) * 4096 + boff[nt]);
      }
      int ky = tap / 3, kx = tap - ky * 3;
      int rr = wv + ky;
      short8 A[2];
#pragma unroll
      for (int wh = 0; wh < 2; ++wh)
        A[wh] = *(const short8*)(&XA[cs & 1][(rr * 160 + abase[wh][kx]) * 8]);
#pragma unroll
      for (int wh = 0; wh < 2; ++wh)
#pragma unroll
        for (int nt = 0; nt < 4; ++nt)
          acc[wh][nt] = __builtin_amdgcn_mfma_f32_16x16x32_bf16(
              A[wh], Bb[t & 1][nt], acc[wh][nt], 0, 0, 0);
    }
    if (cs < 3) __syncthreads();
  }

  // epilogue: BN + gate + store. Wave wv owns row h0+wv, all 64 co.
  // aw gate: head h of row wv lives in AWL[(wv>>1)*2 + h][(wv&1)*32 + ...]
  float s2v[4], t2v[4];
#pragma unroll
  for (int nt = 0; nt < 4; ++nt) {
    int co = blkN * 64 + nt * 16 + l15;
    s2v[nt] = s2[co];
    t2v[nt] = t2[co];
  }
  int h = h0 + wv;
#pragma unroll
  for (int wh = 0; wh < 2; ++wh) {
    int wbase = w0 + wh * 16 + l4 * 4;
    int pb = (wv & 1) * 32 + wh * 16 + l4 * 4;
    f32x4 a0 = *(const f32x4*)(&AWL[(wv >> 1) * 2 + 0][pb]);
    f32x4 a1 = *(const f32x4*)(&AWL[(wv >> 1) * 2 + 1][pb]);
#pragma unroll
    for (int nt = 0; nt < 4; ++nt) {
      int co = blkN * 64 + nt * 16 + l15;
      f32x4 g = (nt >> 1) ? a1 : a0;
      f32x4 o;
#pragma unroll
      for (int rr = 0; rr < 4; ++rr) o[rr] = (acc[wh][nt][rr] * s2v[nt] + t2v[nt]) * g[rr];
      *(f32x4*)(out + (size_t)(b * 128 + co) * 25600 + h * 160 + wbase) = o;
    }
  }
}

// ------------------------------------------------------------------
extern "C" void kernel_launch(void* const* d_in, const int* in_sizes, int n_in,
                              void* d_out, int out_size, void* d_ws, size_t ws_size,
                              hipStream_t stream) {
  (void)in_sizes; (void)n_in; (void)out_size; (void)ws_size;
  const float* x         = (const float*)d_in[0];
  const float* guide     = (const float*)d_in[1];
  const float* w_embed   = (const float*)d_in[2];
  const float* g1        = (const float*)d_in[3];
  const float* b1        = (const float*)d_in[4];
  const float* rm1       = (const float*)d_in[5];
  const float* rv1       = (const float*)d_in[6];
  const float* Wg        = (const float*)d_in[7];
  const float* bg        = (const float*)d_in[8];
  const float* attn_bias = (const float*)d_in[9];
  const float* w_proj    = (const float*)d_in[10];
  const float* g2        = (const float*)d_in[11];
  const float* b2        = (const float*)d_in[12];
  const float* rm2       = (const float*)d_in[13];
  const float* rv2       = (const float*)d_in[14];
  float* out = (float*)d_out;

  char* ws = (char*)d_ws;
  unsigned short* P2   = (unsigned short*)(ws);               // 58,392,576 B
  unsigned short* W1t  = (unsigned short*)(ws + 58392576);    //     16,384 B
  unsigned short* Wpt  = (unsigned short*)(ws + 58408960);    //    294,912 B
  unsigned short* Gpad = (unsigned short*)(ws + 58703872);    //    163,840 B
  float* Cst           = (float*)(ws + 58867712);             //     10,240 B
  float* s2            = (float*)(ws + 58877952);             //        512 B
  float* t2            = (float*)(ws + 58878464);             //        512 B
  // total ws usage: 58,878,976 B

  k_prep_x<<<8 * 112, 256, 0, stream>>>(x, P2);
  k_prep_misc<<<609, 256, 0, stream>>>(w_embed, w_proj, g2, b2, rm2, rv2, W1t, Wpt, s2, t2);
  k_guide<<<640, 64, 0, stream>>>(guide, Wg, bg, g1, b1, rm1, rv1, Gpad, Cst);
  k_mega<<<3200, 256, 0, stream>>>(P2, W1t, Wpt, Gpad, Cst, attn_bias, s2, t2, out);
}

// Round 19
// 187.639 us; speedup vs baseline: 1.0092x; 1.0092x over previous
//
#include <hip/hip_runtime.h>
#include <hip/hip_bf16.h>
#include <stdint.h>

// ---- constants ----
// B=8, Cin=128, H=W=160, Ce=64, NH=4, HC=16, N=80, Cg=512, Co=128
// P2: bf16, cs-major planes [4 cs][8 b][162][176][32 ci]
//     interior (h,w) -> (h+1, w+8); borders zero.
// k_mega (R19 = R18 + depth-2 B pipeline): phase-split (no accE in conv
//   loop) + 4Mx1N conv waves (2 ds_read -> 8 MFMA/tap) + Bb[3][4]
//   prefetch t+2. Register audit: acc 32 AGPR + Bb 48 + A 8 + addr ~20
//   = ~76-80 VGPR < 84 cap @(256,3). R18's regression was depth-1 B
//   (bare L2 latency every tap); R13's was accE+Bb overflow.
// Spill tripwire: WRITE must stay 102.4 MB.

typedef __attribute__((ext_vector_type(8))) short short8;
typedef __attribute__((ext_vector_type(4))) float f32x4;

#define PCH2 ((size_t)8 * 162 * 176 * 32)   // elements per cs-plane

#define GLDS(gp, lp) __builtin_amdgcn_global_load_lds(                         \
    (const __attribute__((address_space(1))) void*)(gp),                       \
    (__attribute__((address_space(3))) void*)(lp), 16, 0, 0)

__device__ __forceinline__ unsigned short f2bf(float f) {
  unsigned int u = __float_as_uint(f);
  u += 0x7fff + ((u >> 16) & 1);   // round-to-nearest-even
  return (unsigned short)(u >> 16);
}

// ------------------------------------------------------------------
// P0: x fp32 NCHW -> bf16 cs-major padded planes, zero borders.
// ------------------------------------------------------------------
__global__ __launch_bounds__(256) void k_prep_x(const float* __restrict__ x,
                                                unsigned short* __restrict__ P2) {
  __shared__ unsigned short T[8192];   // 16 KB
  int b = blockIdx.x / 112, blk = blockIdx.x % 112;
  int tid = threadIdx.x;
  int px = blk * 256 + tid;            // read-phase px (one per thread)
  int hp = px / 176, wp = px - hp * 176;
  bool interior = (px < 28512) && (hp >= 1) && (hp <= 160) && (wp >= 8) && (wp < 168);
  const float* xb = x + (size_t)b * 128 * 25600 + (hp - 1) * 160 + (wp - 8);
  int q = tid >> 2, os = tid & 3;      // store-phase (px-group, chunk)

  for (int cs = 0; cs < 4; ++cs) {
    short8 v[4];
#pragma unroll
    for (int s = 0; s < 4; ++s) {
#pragma unroll
      for (int j = 0; j < 8; ++j) {
        float f = interior ? xb[(size_t)(cs * 32 + s * 8 + j) * 25600] : 0.f;
        v[s][j] = (short)f2bf(f);
      }
    }
    if (cs) __syncthreads();           // prior store-phase reads done
#pragma unroll
    for (int s = 0; s < 4; ++s)
      *(short8*)(&T[(tid * 4 + (s ^ (tid & 3))) * 8]) = v[s];
    __syncthreads();
#pragma unroll
    for (int ph = 0; ph < 4; ++ph) {
      int lpx = ph * 64 + q;
      int opx = blk * 256 + lpx;
      if (opx < 28512) {
        int ohp = opx / 176, owp = opx - ohp * 176;
        size_t obase = (((size_t)b * 162 + ohp) * 176 + owp) * 32 + os * 8;
        short8 w = *(const short8*)(&T[(lpx * 4 + (os ^ (lpx & 3))) * 8]);
        *(short8*)(&P2[(size_t)cs * PCH2 + obase]) = w;
      }
    }
  }
}

// ------------------------------------------------------------------
// P1: weight conversions + BN2 folding
// ------------------------------------------------------------------
__global__ __launch_bounds__(256) void k_prep_misc(
    const float* __restrict__ w_embed, const float* __restrict__ w_proj,
    const float* __restrict__ g2, const float* __restrict__ b2,
    const float* __restrict__ rm2, const float* __restrict__ rv2,
    unsigned short* __restrict__ W1t, unsigned short* __restrict__ Wpt,
    float* __restrict__ s2, float* __restrict__ t2) {
  int idx = blockIdx.x * 256 + threadIdx.x;
  if (idx < 8192) { W1t[idx] = f2bf(w_embed[idx]); return; }
  idx -= 8192;
  if (idx < 147456) {
    int cs = idx / 36864, r = idx - cs * 36864;
    int tap = r >> 12, r2 = r & 4095;
    int co = r2 >> 5, ci5 = r2 & 31;
    int ci = cs * 32 + ci5;
    Wpt[idx] = f2bf(w_proj[(co * 128 + ci) * 9 + tap]);
    return;
  }
  idx -= 147456;
  if (idx < 128) {
    float s = g2[idx] * rsqrtf(rv2[idx] + 1e-3f);
    s2[idx] = s;
    t2[idx] = b2[idx] - rm2[idx] * s;
  }
}

// ------------------------------------------------------------------
// P2k: guide GEMM + BN1 folding
// ------------------------------------------------------------------
__global__ __launch_bounds__(64) void k_guide(
    const float* __restrict__ guide, const float* __restrict__ Wg,
    const float* __restrict__ bg, const float* __restrict__ g1,
    const float* __restrict__ b1, const float* __restrict__ rm1,
    const float* __restrict__ rv1, unsigned short* __restrict__ Gpad,
    float* __restrict__ Cst) {
  int b = blockIdx.x / 80, n = blockIdx.x % 80;
  __shared__ float gs[512];
  const float* gr = guide + ((size_t)b * 80 + n) * 512;
  for (int i = threadIdx.x; i < 512; i += 64) gs[i] = gr[i];
  __syncthreads();
  int ce = threadIdx.x;
  const float* wr = Wg + (size_t)ce * 512;
  float acc = 0.f;
  for (int k = 0; k < 512; k += 4)
    acc += gs[k] * wr[k] + gs[k + 1] * wr[k + 1] + gs[k + 2] * wr[k + 2] +
           gs[k + 3] * wr[k + 3];
  float raw = acc + bg[ce];
  float s1 = g1[ce] * rsqrtf(rv1[ce] + 1e-3f);
  float t1 = b1[ce] - rm1[ce] * s1;
  int head = ce >> 4, c = ce & 15;
  size_t gp = (((size_t)b * 4 + head) * 80 + n) * 32;
  Gpad[gp + c] = f2bf(raw * s1);
  Gpad[gp + 16 + c] = 0;
  float cp = raw * t1;
  cp += __shfl_xor(cp, 1);
  cp += __shfl_xor(cp, 2);
  cp += __shfl_xor(cp, 4);
  cp += __shfl_xor(cp, 8);
  if (c == 0) Cst[((size_t)b * 4 + head) * 80 + n] = cp;
}

// ------------------------------------------------------------------
// K: fused conv+attn, co-split blocks, phase-split, 4Mx1N conv waves,
// depth-2 B register pipeline.
// Block = [4h x 32w px] x [64 co], 3200 blocks, 4 waves.
// LDS: XA 2x15,360 + AWL [4][64] f32 = 31,744 B.
// ------------------------------------------------------------------
__global__ __launch_bounds__(256, 3) void k_mega(
    const unsigned short* __restrict__ P2, const unsigned short* __restrict__ W1t,
    const unsigned short* __restrict__ Wpt, const unsigned short* __restrict__ Gpad,
    const float* __restrict__ Cst, const float* __restrict__ attn_bias,
    const float* __restrict__ s2, const float* __restrict__ t2,
    float* __restrict__ out) {
  __shared__ unsigned short XA[2][7680];
  __shared__ float AWL[4][64];
  int b = blockIdx.x & 7;
  int r = blockIdx.x >> 3;          // 0..399
  int blkN = r & 1;                 // co-half / head-pair select
  int tile = r >> 1;                // 0..199
  int ht = tile / 5, wt = tile - ht * 5;
  int h0 = ht * 4, w0 = wt * 32;
  int tid = threadIdx.x, lane = tid & 63, wv = tid >> 6;
  int l15 = lane & 15, l4 = lane >> 4;
  int mh = wv >> 1, nh = wv & 1;

  // ================= PHASE 1: embed + scores -> AWL (R17-verified) =========
  {
    int a2off[2];
#pragma unroll
    for (int k = 0; k < 2; ++k) {
      int c = (wv * 2 + k) * 64 + lane;   // 0..511
      int rr2 = c >> 7, rem = c & 127;
      int p = rem >> 2, sp = rem & 3;
      int s = sp ^ ((p >> 1) & 3);
      a2off[k] = (int)(((b * 162 + h0 + 1 + rr2) * 176 + (w0 + 8 + p)) * 32 + s * 8);
    }
    int a2base[4];
#pragma unroll
    for (int j = 0; j < 4; ++j) {
      int rr2 = mh * 2 + (j >> 1);
      int p = (j & 1) * 16 + l15;
      a2base[j] = rr2 * 128 + p * 4 + (l4 ^ ((p >> 1) & 3));
    }

    f32x4 accE[4];
#pragma unroll
    for (int j = 0; j < 4; ++j) accE[j] = (f32x4){0.f, 0.f, 0.f, 0.f};

#pragma unroll
    for (int k = 0; k < 2; ++k)
      GLDS(P2 + a2off[k], &XA[0][(wv * 2 + k) * 512]);
    __syncthreads();

#pragma unroll
    for (int cs = 0; cs < 4; ++cs) {
      if (cs < 3) {
#pragma unroll
        for (int k = 0; k < 2; ++k)
          GLDS(P2 + (size_t)(cs + 1) * PCH2 + a2off[k],
               &XA[(cs + 1) & 1][(wv * 2 + k) * 512]);
      }
      short8 BE = *(const short8*)(W1t + (blkN * 32 + nh * 16 + l15) * 128 +
                                   cs * 32 + l4 * 8);
      short8 A2[4];
#pragma unroll
      for (int j = 0; j < 4; ++j)
        A2[j] = *(const short8*)(&XA[cs & 1][a2base[j] * 8]);
#pragma unroll
      for (int j = 0; j < 4; ++j)
        accE[j] = __builtin_amdgcn_mfma_f32_16x16x32_bf16(A2[j], BE, accE[j], 0, 0, 0);
      __syncthreads();
    }

    // E: wave-private [64 px][2 chunks][8] bf16 at element offset wv*1024
    unsigned short* Eb = &XA[0][0];
#pragma unroll
    for (int j = 0; j < 4; ++j)
#pragma unroll
      for (int rr = 0; rr < 4; ++rr) {
        int pxl = (j >> 1) * 32 + (j & 1) * 16 + l4 * 4 + rr;
        int chunk = (l15 >> 3) ^ (pxl & 1);
        Eb[wv * 1024 + pxl * 16 + chunk * 8 + (l15 & 7)] = f2bf(accE[j][rr]);
      }

    const f32x4 zf = (f32x4){0.f, 0.f, 0.f, 0.f};
    int head = blkN * 2 + nh;
    short8 Ga[5];
    f32x4 cst[5];
#pragma unroll
    for (int m5 = 0; m5 < 5; ++m5) {
      Ga[m5] = *(const short8*)(Gpad + (((size_t)b * 4 + head) * 80 + m5 * 16 + l15) * 32 + l4 * 8);
      cst[m5] = *(const f32x4*)(Cst + ((size_t)b * 4 + head) * 80 + m5 * 16 + l4 * 4);
    }
    float bias = attn_bias[head];
#pragma unroll
    for (int nt = 0; nt < 4; ++nt) {
      int pxl = nt * 16 + l15;
      int chr = (l4 & 1) ^ (pxl & 1);   // l4>=2 rereads: garbage x Gpad-zeros = 0
      short8 Bf = *(const short8*)(&Eb[wv * 1024 + pxl * 16 + chr * 8]);
      float mx = -3.0e38f;
#pragma unroll
      for (int m5 = 0; m5 < 5; ++m5) {
        f32x4 sc = __builtin_amdgcn_mfma_f32_16x16x32_bf16(Ga[m5], Bf, zf, 0, 0, 0);
#pragma unroll
        for (int rr = 0; rr < 4; ++rr) mx = fmaxf(mx, sc[rr] + cst[m5][rr]);
      }
      mx = fmaxf(mx, __shfl_xor(mx, 16));
      mx = fmaxf(mx, __shfl_xor(mx, 32));
      if (lane < 16) AWL[wv][nt * 16 + lane] = 1.f / (1.f + __expf(-(mx * 0.25f + bias)));
    }
  }
  __syncthreads();   // E/AWL visible block-wide; XA free for conv staging

  // ================= PHASE 2: 3x3 conv, wave = h-row x 64 co ==============
  size_t aoff[4];
#pragma unroll
  for (int k = 0; k < 4; ++k) {
    int i = wv * 4 + k;
    int c = i * 64 + lane;
    int cc = (c < 960) ? c : 0;
    int row = cc / 160, rem = cc - row * 160;
    int px = rem >> 2, sp = rem & 3;
    int s = sp ^ ((px >> 1) & 3);
    aoff[k] = (((size_t)b * 162 + h0 + row) * 176 + (w0 + 7 + px)) * 32 + s * 8;
  }
  int abase[2][3];
#pragma unroll
  for (int wh = 0; wh < 2; ++wh)
#pragma unroll
    for (int kx = 0; kx < 3; ++kx) {
      int px = wh * 16 + l15 + kx;
      abase[wh][kx] = px * 4 + (l4 ^ ((px >> 1) & 3));
    }
  // B-frag global offsets: full 64-co half per wave (waves share lines -> L1)
  int boff[4];
#pragma unroll
  for (int nt = 0; nt < 4; ++nt)
    boff[nt] = (blkN * 64 + nt * 16 + l15) * 32 + l4 * 8;

  f32x4 acc[2][4];
#pragma unroll
  for (int wh = 0; wh < 2; ++wh)
#pragma unroll
    for (int nt = 0; nt < 4; ++nt) acc[wh][nt] = (f32x4){0.f, 0.f, 0.f, 0.f};

  // prologue: async-stage A(cs=0); init B depth-2 pipeline (3 slots)
#pragma unroll
  for (int k = 0; k < 4; ++k) {
    int i = wv * 4 + k;
    if (i < 15) GLDS(P2 + aoff[k], &XA[0][i * 512]);
  }
  short8 Bb[3][4];
#pragma unroll
  for (int nt = 0; nt < 4; ++nt) {
    Bb[0][nt] = *(const short8*)(Wpt + boff[nt]);
    Bb[1][nt] = *(const short8*)(Wpt + 4096 + boff[nt]);
  }
  __syncthreads();

#pragma unroll
  for (int cs = 0; cs < 4; ++cs) {
    if (cs < 3) {
#pragma unroll
      for (int k = 0; k < 4; ++k) {
        int i = wv * 4 + k;
        if (i < 15)
          GLDS(P2 + (size_t)(cs + 1) * PCH2 + aoff[k], &XA[(cs + 1) & 1][i * 512]);
      }
    }
#pragma unroll
    for (int tap = 0; tap < 9; ++tap) {
      const int t = cs * 9 + tap;
      // prefetch B slab t+2
      if (t + 2 < 36) {
#pragma unroll
        for (int nt = 0; nt < 4; ++nt)
          Bb[(t + 2) % 3][nt] =
              *(const short8*)(Wpt + (size_t)(t + 2) * 4096 + boff[nt]);
      }
      int ky = tap / 3, kx = tap - ky * 3;
      int rr = wv + ky;
      short8 A[2];
#pragma unroll
      for (int wh = 0; wh < 2; ++wh)
        A[wh] = *(const short8*)(&XA[cs & 1][(rr * 160 + abase[wh][kx]) * 8]);
#pragma unroll
      for (int wh = 0; wh < 2; ++wh)
#pragma unroll
        for (int nt = 0; nt < 4; ++nt)
          acc[wh][nt] = __builtin_amdgcn_mfma_f32_16x16x32_bf16(
              A[wh], Bb[t % 3][nt], acc[wh][nt], 0, 0, 0);
    }
    if (cs < 3) __syncthreads();
  }

  // epilogue: BN + gate + store. Wave wv owns row h0+wv, all 64 co.
  // aw gate: head h of row wv lives in AWL[(wv>>1)*2 + h][(wv&1)*32 + ...]
  float s2v[4], t2v[4];
#pragma unroll
  for (int nt = 0; nt < 4; ++nt) {
    int co = blkN * 64 + nt * 16 + l15;
    s2v[nt] = s2[co];
    t2v[nt] = t2[co];
  }
  int h = h0 + wv;
#pragma unroll
  for (int wh = 0; wh < 2; ++wh) {
    int wbase = w0 + wh * 16 + l4 * 4;
    int pb = (wv & 1) * 32 + wh * 16 + l4 * 4;
    f32x4 a0 = *(const f32x4*)(&AWL[(wv >> 1) * 2 + 0][pb]);
    f32x4 a1 = *(const f32x4*)(&AWL[(wv >> 1) * 2 + 1][pb]);
#pragma unroll
    for (int nt = 0; nt < 4; ++nt) {
      int co = blkN * 64 + nt * 16 + l15;
      f32x4 g = (nt >> 1) ? a1 : a0;
      f32x4 o;
#pragma unroll
      for (int rr = 0; rr < 4; ++rr) o[rr] = (acc[wh][nt][rr] * s2v[nt] + t2v[nt]) * g[rr];
      *(f32x4*)(out + (size_t)(b * 128 + co) * 25600 + h * 160 + wbase) = o;
    }
  }
}

// ------------------------------------------------------------------
extern "C" void kernel_launch(void* const* d_in, const int* in_sizes, int n_in,
                              void* d_out, int out_size, void* d_ws, size_t ws_size,
                              hipStream_t stream) {
  (void)in_sizes; (void)n_in; (void)out_size; (void)ws_size;
  const float* x         = (const float*)d_in[0];
  const float* guide     = (const float*)d_in[1];
  const float* w_embed   = (const float*)d_in[2];
  const float* g1        = (const float*)d_in[3];
  const float* b1        = (const float*)d_in[4];
  const float* rm1       = (const float*)d_in[5];
  const float* rv1       = (const float*)d_in[6];
  const float* Wg        = (const float*)d_in[7];
  const float* bg        = (const float*)d_in[8];
  const float* attn_bias = (const float*)d_in[9];
  const float* w_proj    = (const float*)d_in[10];
  const float* g2        = (const float*)d_in[11];
  const float* b2        = (const float*)d_in[12];
  const float* rm2       = (const float*)d_in[13];
  const float* rv2       = (const float*)d_in[14];
  float* out = (float*)d_out;

  char* ws = (char*)d_ws;
  unsigned short* P2   = (unsigned short*)(ws);               // 58,392,576 B
  unsigned short* W1t  = (unsigned short*)(ws + 58392576);    //     16,384 B
  unsigned short* Wpt  = (unsigned short*)(ws + 58408960);    //    294,912 B
  unsigned short* Gpad = (unsigned short*)(ws + 58703872);    //    163,840 B
  float* Cst           = (float*)(ws + 58867712);             //     10,240 B
  float* s2            = (float*)(ws + 58877952);             //        512 B
  float* t2            = (float*)(ws + 58878464);             //        512 B
  // total ws usage: 58,878,976 B

  k_prep_x<<<8 * 112, 256, 0, stream>>>(x, P2);
  k_prep_misc<<<609, 256, 0, stream>>>(w_embed, w_proj, g2, b2, rm2, rv2, W1t, Wpt, s2, t2);
  k_guide<<<640, 64, 0, stream>>>(guide, Wg, bg, g1, b1, rm1, rv1, Gpad, Cst);
  k_mega<<<3200, 256, 0, stream>>>(P2, W1t, Wpt, Gpad, Cst, attn_bias, s2, t2, out);
}

// Round 20
// 141.116 us; speedup vs baseline: 1.3419x; 1.3297x over previous
//
#include <hip/hip_runtime.h>
#include <hip/hip_bf16.h>
#include <stdint.h>

// ---- constants ----
// B=8, Cin=128, H=W=160, Ce=64, NH=4, HC=16, N=80, Cg=512, Co=128
// P2: bf16, cs-major planes [4 cs][8 b][162][176][32 ci]
//     interior (h,w) -> (h+1, w+8); borders zero.
// k_mega (R20 = R12, the measured optimum): async global_load_lds
//   A-staging (linear LDS dest, pre-swizzled coalesced source),
//   B reg pipeline depth 2, 2Mx2N waves, (256,3).
// Register rule (R7/R11/R13/R15 evidence): gfx950 unified VGPR+AGPR
//   file; this kernel needs ~76 arch-VGPR + 48 AGPR. (256,3) fits;
//   tighter bounds spill (tell: WRITE >> 102.4 MB).
// Plateau note (R13-R19): k_mega ~103 us is a serialized-pipe plateau
//   (MFMA 29 + LDS 24-36 + VALU 18 us), insensitive to occupancy
//   21->40% and to MFMA:LDS ratio re-shapes (those go B-issue-bound).

typedef __attribute__((ext_vector_type(8))) short short8;
typedef __attribute__((ext_vector_type(4))) float f32x4;

#define PCH2 ((size_t)8 * 162 * 176 * 32)   // elements per cs-plane

#define GLDS(gp, lp) __builtin_amdgcn_global_load_lds(                         \
    (const __attribute__((address_space(1))) void*)(gp),                       \
    (__attribute__((address_space(3))) void*)(lp), 16, 0, 0)

__device__ __forceinline__ unsigned short f2bf(float f) {
  unsigned int u = __float_as_uint(f);
  u += 0x7fff + ((u >> 16) & 1);   // round-to-nearest-even
  return (unsigned short)(u >> 16);
}

// ------------------------------------------------------------------
// P0: x fp32 NCHW -> bf16 cs-major padded planes, zero borders.
// LDS-transpose bounce: reads lane=px fully coalesced (256 B/instr);
// stores 16 B lane-consecutive (1 KB dense per wave-instr).
// ------------------------------------------------------------------
__global__ __launch_bounds__(256) void k_prep_x(const float* __restrict__ x,
                                                unsigned short* __restrict__ P2) {
  __shared__ unsigned short T[8192];   // 16 KB
  int b = blockIdx.x / 112, blk = blockIdx.x % 112;
  int tid = threadIdx.x;
  int px = blk * 256 + tid;            // read-phase px (one per thread)
  int hp = px / 176, wp = px - hp * 176;
  bool interior = (px < 28512) && (hp >= 1) && (hp <= 160) && (wp >= 8) && (wp < 168);
  const float* xb = x + (size_t)b * 128 * 25600 + (hp - 1) * 160 + (wp - 8);
  int q = tid >> 2, os = tid & 3;      // store-phase (px-group, chunk)

  for (int cs = 0; cs < 4; ++cs) {
    short8 v[4];
#pragma unroll
    for (int s = 0; s < 4; ++s) {
#pragma unroll
      for (int j = 0; j < 8; ++j) {
        float f = interior ? xb[(size_t)(cs * 32 + s * 8 + j) * 25600] : 0.f;
        v[s][j] = (short)f2bf(f);
      }
    }
    if (cs) __syncthreads();           // prior store-phase reads done
#pragma unroll
    for (int s = 0; s < 4; ++s)
      *(short8*)(&T[(tid * 4 + (s ^ (tid & 3))) * 8]) = v[s];
    __syncthreads();
#pragma unroll
    for (int ph = 0; ph < 4; ++ph) {
      int lpx = ph * 64 + q;
      int opx = blk * 256 + lpx;
      if (opx < 28512) {
        int ohp = opx / 176, owp = opx - ohp * 176;
        size_t obase = (((size_t)b * 162 + ohp) * 176 + owp) * 32 + os * 8;
        short8 w = *(const short8*)(&T[(lpx * 4 + (os ^ (lpx & 3))) * 8]);
        *(short8*)(&P2[(size_t)cs * PCH2 + obase]) = w;
      }
    }
  }
}

// ------------------------------------------------------------------
// P1: weight conversions + BN2 folding
//   W1t [64 ce][128 ci] bf16
//   Wpt [4 cs][9 tap][128 co][32 ci] bf16   (slab t = cs*9+tap at t*4096)
//   s2,t2 [128] f32
// ------------------------------------------------------------------
__global__ __launch_bounds__(256) void k_prep_misc(
    const float* __restrict__ w_embed, const float* __restrict__ w_proj,
    const float* __restrict__ g2, const float* __restrict__ b2,
    const float* __restrict__ rm2, const float* __restrict__ rv2,
    unsigned short* __restrict__ W1t, unsigned short* __restrict__ Wpt,
    float* __restrict__ s2, float* __restrict__ t2) {
  int idx = blockIdx.x * 256 + threadIdx.x;
  if (idx < 8192) { W1t[idx] = f2bf(w_embed[idx]); return; }
  idx -= 8192;
  if (idx < 147456) {
    int cs = idx / 36864, r = idx - cs * 36864;
    int tap = r >> 12, r2 = r & 4095;
    int co = r2 >> 5, ci5 = r2 & 31;
    int ci = cs * 32 + ci5;
    Wpt[idx] = f2bf(w_proj[(co * 128 + ci) * 9 + tap]);
    return;
  }
  idx -= 147456;
  if (idx < 128) {
    float s = g2[idx] * rsqrtf(rv2[idx] + 1e-3f);
    s2[idx] = s;
    t2[idx] = b2[idx] - rm2[idx] * s;
  }
}

// ------------------------------------------------------------------
// P2k: guide GEMM + BN1 folding
//   Gpad [8][4][80][32] bf16  (k<16: g_raw*s1 ; k>=16: 0)
//   Cst  [8][4][80] f32       (dot(g_raw, t1) per head)
// ------------------------------------------------------------------
__global__ __launch_bounds__(64) void k_guide(
    const float* __restrict__ guide, const float* __restrict__ Wg,
    const float* __restrict__ bg, const float* __restrict__ g1,
    const float* __restrict__ b1, const float* __restrict__ rm1,
    const float* __restrict__ rv1, unsigned short* __restrict__ Gpad,
    float* __restrict__ Cst) {
  int b = blockIdx.x / 80, n = blockIdx.x % 80;
  __shared__ float gs[512];
  const float* gr = guide + ((size_t)b * 80 + n) * 512;
  for (int i = threadIdx.x; i < 512; i += 64) gs[i] = gr[i];
  __syncthreads();
  int ce = threadIdx.x;
  const float* wr = Wg + (size_t)ce * 512;
  float acc = 0.f;
  for (int k = 0; k < 512; k += 4)
    acc += gs[k] * wr[k] + gs[k + 1] * wr[k + 1] + gs[k + 2] * wr[k + 2] +
           gs[k + 3] * wr[k + 3];
  float raw = acc + bg[ce];
  float s1 = g1[ce] * rsqrtf(rv1[ce] + 1e-3f);
  float t1 = b1[ce] - rm1[ce] * s1;
  int head = ce >> 4, c = ce & 15;
  size_t gp = (((size_t)b * 4 + head) * 80 + n) * 32;
  Gpad[gp + c] = f2bf(raw * s1);
  Gpad[gp + 16 + c] = 0;
  float cp = raw * t1;
  cp += __shfl_xor(cp, 1);
  cp += __shfl_xor(cp, 2);
  cp += __shfl_xor(cp, 4);
  cp += __shfl_xor(cp, 8);
  if (c == 0) Cst[((size_t)b * 4 + head) * 80 + n] = cp;
}

// ------------------------------------------------------------------
// K: fused conv+attn, co-split blocks, async A staging.
// Block = [4h x 32w px] x [64 co], 3200 blocks, 4 waves = 2M x 2N.
// LDS: XA 2x15,360 B; E (8 KB wave-private) + AWL (1 KB) overlay XA[0].
// A: global_load_lds dbuf, 15 wave-instrs/buffer (wave wv: i=wv*4..+3, i<15),
//    chunk c = i*64+lane; source pre-swizzled (slot s = sp^((px>>1)&3)).
// B: register pipeline from L2, depth 2.
// ------------------------------------------------------------------
__global__ __launch_bounds__(256, 3) void k_mega(
    const unsigned short* __restrict__ P2, const unsigned short* __restrict__ W1t,
    const unsigned short* __restrict__ Wpt, const unsigned short* __restrict__ Gpad,
    const float* __restrict__ Cst, const float* __restrict__ attn_bias,
    const float* __restrict__ s2, const float* __restrict__ t2,
    float* __restrict__ out) {
  __shared__ unsigned short XA[2][7680];
  int b = blockIdx.x & 7;
  int r = blockIdx.x >> 3;          // 0..399
  int blkN = r & 1;                 // co-half / head-pair select
  int tile = r >> 1;                // 0..199
  int ht = tile / 5, wt = tile - ht * 5;
  int h0 = ht * 4, w0 = wt * 32;
  int tid = threadIdx.x, lane = tid & 63, wv = tid >> 6;
  int l15 = lane & 15, l4 = lane >> 4;
  int mh = wv >> 1, nh = wv & 1;

  // A staging source offsets: instr slot k -> i = wv*4+k, chunk c = i*64+lane
  size_t aoff[4];
#pragma unroll
  for (int k = 0; k < 4; ++k) {
    int i = wv * 4 + k;
    int c = i * 64 + lane;
    int cc = (c < 960) ? c : 0;
    int row = cc / 160, rem = cc - row * 160;
    int px = rem >> 2, sp = rem & 3;
    int s = sp ^ ((px >> 1) & 3);
    aoff[k] = (((size_t)b * 162 + h0 + row) * 176 + (w0 + 7 + px)) * 32 + s * 8;
  }
  // A-frag read chunk bases (row term added per tap)
  int abase[2][3];
#pragma unroll
  for (int wh = 0; wh < 2; ++wh)
#pragma unroll
    for (int kx = 0; kx < 3; ++kx) {
      int px = wh * 16 + l15 + kx;
      abase[wh][kx] = px * 4 + (l4 ^ ((px >> 1) & 3));
    }
  // B-frag global offsets (2 per wave, this block's co-half)
  int boff2[2];
#pragma unroll
  for (int nt = 0; nt < 2; ++nt)
    boff2[nt] = (blkN * 64 + nh * 32 + nt * 16 + l15) * 32 + l4 * 8;

  f32x4 acc[4][2], accE[4];
#pragma unroll
  for (int j = 0; j < 4; ++j) {
    acc[j][0] = (f32x4){0.f, 0.f, 0.f, 0.f};
    acc[j][1] = (f32x4){0.f, 0.f, 0.f, 0.f};
    accE[j]   = (f32x4){0.f, 0.f, 0.f, 0.f};
  }

  // prologue: async-stage A(cs=0); init B pipeline
#pragma unroll
  for (int k = 0; k < 4; ++k) {
    int i = wv * 4 + k;
    if (i < 15) GLDS(P2 + aoff[k], &XA[0][i * 512]);
  }
  short8 Bb[3][2];
#pragma unroll
  for (int nt = 0; nt < 2; ++nt) {
    Bb[0][nt] = *(const short8*)(Wpt + boff2[nt]);
    Bb[1][nt] = *(const short8*)(Wpt + 4096 + boff2[nt]);
  }
  __syncthreads();

#pragma unroll
  for (int cs = 0; cs < 4; ++cs) {
    // async-issue next A buffer (drains at this cs's ending barrier)
    if (cs < 3) {
#pragma unroll
      for (int k = 0; k < 4; ++k) {
        int i = wv * 4 + k;
        if (i < 15)
          GLDS(P2 + (size_t)(cs + 1) * PCH2 + aoff[k], &XA[(cs + 1) & 1][i * 512]);
      }
    }
#pragma unroll
    for (int tap = 0; tap < 9; ++tap) {
      const int t = cs * 9 + tap;
      // prefetch B slab t+2
      if (t + 2 < 36) {
#pragma unroll
        for (int nt = 0; nt < 2; ++nt)
          Bb[(t + 2) % 3][nt] =
              *(const short8*)(Wpt + (size_t)(t + 2) * 4096 + boff2[nt]);
      }
      int ky = tap / 3, kx = tap - ky * 3;
      short8 A[4];
#pragma unroll
      for (int j = 0; j < 4; ++j) {
        int rr = mh * 2 + (j >> 1) + ky;
        A[j] = *(const short8*)(&XA[cs & 1][(rr * 160 + abase[j & 1][kx]) * 8]);
      }
      if (tap == 4) {  // embed rides the center tap's A-frags (this wave's head)
        short8 BE = *(const short8*)(W1t + (blkN * 32 + nh * 16 + l15) * 128 +
                                     cs * 32 + l4 * 8);
#pragma unroll
        for (int j = 0; j < 4; ++j)
          accE[j] = __builtin_amdgcn_mfma_f32_16x16x32_bf16(A[j], BE, accE[j], 0, 0, 0);
      }
#pragma unroll
      for (int j = 0; j < 4; ++j)
#pragma unroll
        for (int nt = 0; nt < 2; ++nt)
          acc[j][nt] = __builtin_amdgcn_mfma_f32_16x16x32_bf16(
              A[j], Bb[t % 3][nt], acc[j][nt], 0, 0, 0);
    }
    if (cs < 3) __syncthreads();
  }
  __syncthreads();  // all XA reads done; overlay E + AWL on XA[0]

  // E: wave-private [64 px][2 chunks][8] bf16 at element offset wv*1024
  unsigned short* Eb = &XA[0][0];
  float* AWLf = (float*)(&XA[0][0] + 4096);   // after E (8 KB)
#pragma unroll
  for (int j = 0; j < 4; ++j)
#pragma unroll
    for (int rr = 0; rr < 4; ++rr) {
      int pxl = (j >> 1) * 32 + (j & 1) * 16 + l4 * 4 + rr;  // within-wave px
      int chunk = (l15 >> 3) ^ (pxl & 1);
      Eb[wv * 1024 + pxl * 16 + chunk * 8 + (l15 & 7)] = f2bf(accE[j][rr]);
    }

  // scores + max + sigmoid -> AWL (all wave-private; no block barrier)
  const f32x4 zf = (f32x4){0.f, 0.f, 0.f, 0.f};
  int head = blkN * 2 + nh;
  short8 Ga[5];
  f32x4 cst[5];
#pragma unroll
  for (int m5 = 0; m5 < 5; ++m5) {
    Ga[m5] = *(const short8*)(Gpad + (((size_t)b * 4 + head) * 80 + m5 * 16 + l15) * 32 + l4 * 8);
    cst[m5] = *(const f32x4*)(Cst + ((size_t)b * 4 + head) * 80 + m5 * 16 + l4 * 4);
  }
  float bias = attn_bias[head];
#pragma unroll
  for (int nt = 0; nt < 4; ++nt) {
    int pxl = nt * 16 + l15;
    int chr = (l4 & 1) ^ (pxl & 1);   // l4>=2 rereads: any data x Gpad-zeros = 0
    short8 Bf = *(const short8*)(&Eb[wv * 1024 + pxl * 16 + chr * 8]);
    float mx = -3.0e38f;
#pragma unroll
    for (int m5 = 0; m5 < 5; ++m5) {
      f32x4 s = __builtin_amdgcn_mfma_f32_16x16x32_bf16(Ga[m5], Bf, zf, 0, 0, 0);
#pragma unroll
      for (int rr = 0; rr < 4; ++rr) mx = fmaxf(mx, s[rr] + cst[m5][rr]);
    }
    mx = fmaxf(mx, __shfl_xor(mx, 16));
    mx = fmaxf(mx, __shfl_xor(mx, 32));
    if (lane < 16) AWLf[wv * 64 + nt * 16 + lane] = 1.f / (1.f + __expf(-(mx * 0.25f + bias)));
  }

  // epilogue: BN + gate + store (wave-private AWL)
  float s2v[2], t2v[2];
#pragma unroll
  for (int nt = 0; nt < 2; ++nt) {
    int co = blkN * 64 + nh * 32 + nt * 16 + l15;
    s2v[nt] = s2[co];
    t2v[nt] = t2[co];
  }
#pragma unroll
  for (int j = 0; j < 4; ++j) {
    int h = h0 + mh * 2 + (j >> 1);
    int wbase = w0 + (j & 1) * 16 + l4 * 4;
    int pb = (j >> 1) * 32 + (j & 1) * 16 + l4 * 4;
    f32x4 a0 = *(const f32x4*)(&AWLf[wv * 64 + pb]);
#pragma unroll
    for (int nt = 0; nt < 2; ++nt) {
      int co = blkN * 64 + nh * 32 + nt * 16 + l15;
      f32x4 o;
#pragma unroll
      for (int rr = 0; rr < 4; ++rr) o[rr] = (acc[j][nt][rr] * s2v[nt] + t2v[nt]) * a0[rr];
      *(f32x4*)(out + (size_t)(b * 128 + co) * 25600 + h * 160 + wbase) = o;
    }
  }
}

// ------------------------------------------------------------------
extern "C" void kernel_launch(void* const* d_in, const int* in_sizes, int n_in,
                              void* d_out, int out_size, void* d_ws, size_t ws_size,
                              hipStream_t stream) {
  (void)in_sizes; (void)n_in; (void)out_size; (void)ws_size;
  const float* x         = (const float*)d_in[0];
  const float* guide     = (const float*)d_in[1];
  const float* w_embed   = (const float*)d_in[2];
  const float* g1        = (const float*)d_in[3];
  const float* b1        = (const float*)d_in[4];
  const float* rm1       = (const float*)d_in[5];
  const float* rv1       = (const float*)d_in[6];
  const float* Wg        = (const float*)d_in[7];
  const float* bg        = (const float*)d_in[8];
  const float* attn_bias = (const float*)d_in[9];
  const float* w_proj    = (const float*)d_in[10];
  const float* g2        = (const float*)d_in[11];
  const float* b2        = (const float*)d_in[12];
  const float* rm2       = (const float*)d_in[13];
  const float* rv2       = (const float*)d_in[14];
  float* out = (float*)d_out;

  char* ws = (char*)d_ws;
  unsigned short* P2   = (unsigned short*)(ws);               // 58,392,576 B
  unsigned short* W1t  = (unsigned short*)(ws + 58392576);    //     16,384 B
  unsigned short* Wpt  = (unsigned short*)(ws + 58408960);    //    294,912 B
  unsigned short* Gpad = (unsigned short*)(ws + 58703872);    //    163,840 B
  float* Cst           = (float*)(ws + 58867712);             //     10,240 B
  float* s2            = (float*)(ws + 58877952);             //        512 B
  float* t2            = (float*)(ws + 58878464);             //        512 B
  // total ws usage: 58,878,976 B

  k_prep_x<<<8 * 112, 256, 0, stream>>>(x, P2);
  k_prep_misc<<<609, 256, 0, stream>>>(w_embed, w_proj, g2, b2, rm2, rv2, W1t, Wpt, s2, t2);
  k_guide<<<640, 64, 0, stream>>>(guide, Wg, bg, g1, b1, rm1, rv1, Gpad, Cst);
  k_mega<<<3200, 256, 0, stream>>>(P2, W1t, Wpt, Gpad, Cst, attn_bias, s2, t2, out);
}

// Round 21
// 138.200 us; speedup vs baseline: 1.3703x; 1.0211x over previous
//
#include <hip/hip_runtime.h>
#include <hip/hip_bf16.h>
#include <stdint.h>

// ---- constants ----
// B=8, Cin=128, H=W=160, Ce=64, NH=4, HC=16, N=80, Cg=512, Co=128
// P2: bf16, cs-major planes [4 cs][8 b][162][176][32 ci]
//     interior (h,w) -> (h+1, w+8); borders zero.
// k_mega (R21 = R20 + GLDS issue-point moved to tap==2): vmcnt is a
//   FIFO by issue order (m135) -- issuing the 15 staging GLDS before
//   the tap loop made every B-frag wait from tap 2 on drain the whole
//   staging batch first. Moving the GLDS issue after taps 0-1's B
//   prefetches decouples them. Pure code motion; same barrier guards.
// Register rule (R7/R11/R13/R15): ~76 arch-VGPR + 48 AGPR; (256,3)
//   fits, tighter bounds spill (tell: WRITE >> 102.4 MB).
// Plateau note (R13-R19): ~103 us serialized-pipe plateau, insensitive
//   to occupancy 21->40% and MFMA:LDS re-shapes (those go B-issue-bound).

typedef __attribute__((ext_vector_type(8))) short short8;
typedef __attribute__((ext_vector_type(4))) float f32x4;

#define PCH2 ((size_t)8 * 162 * 176 * 32)   // elements per cs-plane

#define GLDS(gp, lp) __builtin_amdgcn_global_load_lds(                         \
    (const __attribute__((address_space(1))) void*)(gp),                       \
    (__attribute__((address_space(3))) void*)(lp), 16, 0, 0)

__device__ __forceinline__ unsigned short f2bf(float f) {
  unsigned int u = __float_as_uint(f);
  u += 0x7fff + ((u >> 16) & 1);   // round-to-nearest-even
  return (unsigned short)(u >> 16);
}

// ------------------------------------------------------------------
// P0: x fp32 NCHW -> bf16 cs-major padded planes, zero borders.
// LDS-transpose bounce: reads lane=px fully coalesced (256 B/instr);
// stores 16 B lane-consecutive (1 KB dense per wave-instr).
// ------------------------------------------------------------------
__global__ __launch_bounds__(256) void k_prep_x(const float* __restrict__ x,
                                                unsigned short* __restrict__ P2) {
  __shared__ unsigned short T[8192];   // 16 KB
  int b = blockIdx.x / 112, blk = blockIdx.x % 112;
  int tid = threadIdx.x;
  int px = blk * 256 + tid;            // read-phase px (one per thread)
  int hp = px / 176, wp = px - hp * 176;
  bool interior = (px < 28512) && (hp >= 1) && (hp <= 160) && (wp >= 8) && (wp < 168);
  const float* xb = x + (size_t)b * 128 * 25600 + (hp - 1) * 160 + (wp - 8);
  int q = tid >> 2, os = tid & 3;      // store-phase (px-group, chunk)

  for (int cs = 0; cs < 4; ++cs) {
    short8 v[4];
#pragma unroll
    for (int s = 0; s < 4; ++s) {
#pragma unroll
      for (int j = 0; j < 8; ++j) {
        float f = interior ? xb[(size_t)(cs * 32 + s * 8 + j) * 25600] : 0.f;
        v[s][j] = (short)f2bf(f);
      }
    }
    if (cs) __syncthreads();           // prior store-phase reads done
#pragma unroll
    for (int s = 0; s < 4; ++s)
      *(short8*)(&T[(tid * 4 + (s ^ (tid & 3))) * 8]) = v[s];
    __syncthreads();
#pragma unroll
    for (int ph = 0; ph < 4; ++ph) {
      int lpx = ph * 64 + q;
      int opx = blk * 256 + lpx;
      if (opx < 28512) {
        int ohp = opx / 176, owp = opx - ohp * 176;
        size_t obase = (((size_t)b * 162 + ohp) * 176 + owp) * 32 + os * 8;
        short8 w = *(const short8*)(&T[(lpx * 4 + (os ^ (lpx & 3))) * 8]);
        *(short8*)(&P2[(size_t)cs * PCH2 + obase]) = w;
      }
    }
  }
}

// ------------------------------------------------------------------
// P1: weight conversions + BN2 folding
//   W1t [64 ce][128 ci] bf16
//   Wpt [4 cs][9 tap][128 co][32 ci] bf16   (slab t = cs*9+tap at t*4096)
//   s2,t2 [128] f32
// ------------------------------------------------------------------
__global__ __launch_bounds__(256) void k_prep_misc(
    const float* __restrict__ w_embed, const float* __restrict__ w_proj,
    const float* __restrict__ g2, const float* __restrict__ b2,
    const float* __restrict__ rm2, const float* __restrict__ rv2,
    unsigned short* __restrict__ W1t, unsigned short* __restrict__ Wpt,
    float* __restrict__ s2, float* __restrict__ t2) {
  int idx = blockIdx.x * 256 + threadIdx.x;
  if (idx < 8192) { W1t[idx] = f2bf(w_embed[idx]); return; }
  idx -= 8192;
  if (idx < 147456) {
    int cs = idx / 36864, r = idx - cs * 36864;
    int tap = r >> 12, r2 = r & 4095;
    int co = r2 >> 5, ci5 = r2 & 31;
    int ci = cs * 32 + ci5;
    Wpt[idx] = f2bf(w_proj[(co * 128 + ci) * 9 + tap]);
    return;
  }
  idx -= 147456;
  if (idx < 128) {
    float s = g2[idx] * rsqrtf(rv2[idx] + 1e-3f);
    s2[idx] = s;
    t2[idx] = b2[idx] - rm2[idx] * s;
  }
}

// ------------------------------------------------------------------
// P2k: guide GEMM + BN1 folding
//   Gpad [8][4][80][32] bf16  (k<16: g_raw*s1 ; k>=16: 0)
//   Cst  [8][4][80] f32       (dot(g_raw, t1) per head)
// ------------------------------------------------------------------
__global__ __launch_bounds__(64) void k_guide(
    const float* __restrict__ guide, const float* __restrict__ Wg,
    const float* __restrict__ bg, const float* __restrict__ g1,
    const float* __restrict__ b1, const float* __restrict__ rm1,
    const float* __restrict__ rv1, unsigned short* __restrict__ Gpad,
    float* __restrict__ Cst) {
  int b = blockIdx.x / 80, n = blockIdx.x % 80;
  __shared__ float gs[512];
  const float* gr = guide + ((size_t)b * 80 + n) * 512;
  for (int i = threadIdx.x; i < 512; i += 64) gs[i] = gr[i];
  __syncthreads();
  int ce = threadIdx.x;
  const float* wr = Wg + (size_t)ce * 512;
  float acc = 0.f;
  for (int k = 0; k < 512; k += 4)
    acc += gs[k] * wr[k] + gs[k + 1] * wr[k + 1] + gs[k + 2] * wr[k + 2] +
           gs[k + 3] * wr[k + 3];
  float raw = acc + bg[ce];
  float s1 = g1[ce] * rsqrtf(rv1[ce] + 1e-3f);
  float t1 = b1[ce] - rm1[ce] * s1;
  int head = ce >> 4, c = ce & 15;
  size_t gp = (((size_t)b * 4 + head) * 80 + n) * 32;
  Gpad[gp + c] = f2bf(raw * s1);
  Gpad[gp + 16 + c] = 0;
  float cp = raw * t1;
  cp += __shfl_xor(cp, 1);
  cp += __shfl_xor(cp, 2);
  cp += __shfl_xor(cp, 4);
  cp += __shfl_xor(cp, 8);
  if (c == 0) Cst[((size_t)b * 4 + head) * 80 + n] = cp;
}

// ------------------------------------------------------------------
// K: fused conv+attn, co-split blocks, async A staging.
// Block = [4h x 32w px] x [64 co], 3200 blocks, 4 waves = 2M x 2N.
// LDS: XA 2x15,360 B; E (8 KB wave-private) + AWL (1 KB) overlay XA[0].
// A: global_load_lds dbuf, 15 wave-instrs/buffer, issued at tap==2
//    (after taps 0-1's B prefetches; vmcnt FIFO decoupling).
// B: register pipeline from L2, depth 2.
// ------------------------------------------------------------------
__global__ __launch_bounds__(256, 3) void k_mega(
    const unsigned short* __restrict__ P2, const unsigned short* __restrict__ W1t,
    const unsigned short* __restrict__ Wpt, const unsigned short* __restrict__ Gpad,
    const float* __restrict__ Cst, const float* __restrict__ attn_bias,
    const float* __restrict__ s2, const float* __restrict__ t2,
    float* __restrict__ out) {
  __shared__ unsigned short XA[2][7680];
  int b = blockIdx.x & 7;
  int r = blockIdx.x >> 3;          // 0..399
  int blkN = r & 1;                 // co-half / head-pair select
  int tile = r >> 1;                // 0..199
  int ht = tile / 5, wt = tile - ht * 5;
  int h0 = ht * 4, w0 = wt * 32;
  int tid = threadIdx.x, lane = tid & 63, wv = tid >> 6;
  int l15 = lane & 15, l4 = lane >> 4;
  int mh = wv >> 1, nh = wv & 1;

  // A staging source offsets: instr slot k -> i = wv*4+k, chunk c = i*64+lane
  size_t aoff[4];
#pragma unroll
  for (int k = 0; k < 4; ++k) {
    int i = wv * 4 + k;
    int c = i * 64 + lane;
    int cc = (c < 960) ? c : 0;
    int row = cc / 160, rem = cc - row * 160;
    int px = rem >> 2, sp = rem & 3;
    int s = sp ^ ((px >> 1) & 3);
    aoff[k] = (((size_t)b * 162 + h0 + row) * 176 + (w0 + 7 + px)) * 32 + s * 8;
  }
  // A-frag read chunk bases (row term added per tap)
  int abase[2][3];
#pragma unroll
  for (int wh = 0; wh < 2; ++wh)
#pragma unroll
    for (int kx = 0; kx < 3; ++kx) {
      int px = wh * 16 + l15 + kx;
      abase[wh][kx] = px * 4 + (l4 ^ ((px >> 1) & 3));
    }
  // B-frag global offsets (2 per wave, this block's co-half)
  int boff2[2];
#pragma unroll
  for (int nt = 0; nt < 2; ++nt)
    boff2[nt] = (blkN * 64 + nh * 32 + nt * 16 + l15) * 32 + l4 * 8;

  f32x4 acc[4][2], accE[4];
#pragma unroll
  for (int j = 0; j < 4; ++j) {
    acc[j][0] = (f32x4){0.f, 0.f, 0.f, 0.f};
    acc[j][1] = (f32x4){0.f, 0.f, 0.f, 0.f};
    accE[j]   = (f32x4){0.f, 0.f, 0.f, 0.f};
  }

  // prologue: async-stage A(cs=0); init B pipeline
#pragma unroll
  for (int k = 0; k < 4; ++k) {
    int i = wv * 4 + k;
    if (i < 15) GLDS(P2 + aoff[k], &XA[0][i * 512]);
  }
  short8 Bb[3][2];
#pragma unroll
  for (int nt = 0; nt < 2; ++nt) {
    Bb[0][nt] = *(const short8*)(Wpt + boff2[nt]);
    Bb[1][nt] = *(const short8*)(Wpt + 4096 + boff2[nt]);
  }
  __syncthreads();

#pragma unroll
  for (int cs = 0; cs < 4; ++cs) {
#pragma unroll
    for (int tap = 0; tap < 9; ++tap) {
      const int t = cs * 9 + tap;
      // prefetch B slab t+2 (issued BEFORE the staging batch each cs)
      if (t + 2 < 36) {
#pragma unroll
        for (int nt = 0; nt < 2; ++nt)
          Bb[(t + 2) % 3][nt] =
              *(const short8*)(Wpt + (size_t)(t + 2) * 4096 + boff2[nt]);
      }
      // async-issue next A buffer mid-loop (vmcnt FIFO decoupling):
      // taps 2-3's B-waits (loads issued pre-GLDS) aren't blocked by
      // the staging batch; GLDS still has 7 taps + barrier to land.
      if (tap == 2 && cs < 3) {
#pragma unroll
        for (int k = 0; k < 4; ++k) {
          int i = wv * 4 + k;
          if (i < 15)
            GLDS(P2 + (size_t)(cs + 1) * PCH2 + aoff[k], &XA[(cs + 1) & 1][i * 512]);
        }
      }
      int ky = tap / 3, kx = tap - ky * 3;
      short8 A[4];
#pragma unroll
      for (int j = 0; j < 4; ++j) {
        int rr = mh * 2 + (j >> 1) + ky;
        A[j] = *(const short8*)(&XA[cs & 1][(rr * 160 + abase[j & 1][kx]) * 8]);
      }
      if (tap == 4) {  // embed rides the center tap's A-frags (this wave's head)
        short8 BE = *(const short8*)(W1t + (blkN * 32 + nh * 16 + l15) * 128 +
                                     cs * 32 + l4 * 8);
#pragma unroll
        for (int j = 0; j < 4; ++j)
          accE[j] = __builtin_amdgcn_mfma_f32_16x16x32_bf16(A[j], BE, accE[j], 0, 0, 0);
      }
#pragma unroll
      for (int j = 0; j < 4; ++j)
#pragma unroll
        for (int nt = 0; nt < 2; ++nt)
          acc[j][nt] = __builtin_amdgcn_mfma_f32_16x16x32_bf16(
              A[j], Bb[t % 3][nt], acc[j][nt], 0, 0, 0);
    }
    if (cs < 3) __syncthreads();
  }
  __syncthreads();  // all XA reads done; overlay E + AWL on XA[0]

  // E: wave-private [64 px][2 chunks][8] bf16 at element offset wv*1024
  unsigned short* Eb = &XA[0][0];
  float* AWLf = (float*)(&XA[0][0] + 4096);   // after E (8 KB)
#pragma unroll
  for (int j = 0; j < 4; ++j)
#pragma unroll
    for (int rr = 0; rr < 4; ++rr) {
      int pxl = (j >> 1) * 32 + (j & 1) * 16 + l4 * 4 + rr;  // within-wave px
      int chunk = (l15 >> 3) ^ (pxl & 1);
      Eb[wv * 1024 + pxl * 16 + chunk * 8 + (l15 & 7)] = f2bf(accE[j][rr]);
    }

  // scores + max + sigmoid -> AWL (all wave-private; no block barrier)
  const f32x4 zf = (f32x4){0.f, 0.f, 0.f, 0.f};
  int head = blkN * 2 + nh;
  short8 Ga[5];
  f32x4 cst[5];
#pragma unroll
  for (int m5 = 0; m5 < 5; ++m5) {
    Ga[m5] = *(const short8*)(Gpad + (((size_t)b * 4 + head) * 80 + m5 * 16 + l15) * 32 + l4 * 8);
    cst[m5] = *(const f32x4*)(Cst + ((size_t)b * 4 + head) * 80 + m5 * 16 + l4 * 4);
  }
  float bias = attn_bias[head];
#pragma unroll
  for (int nt = 0; nt < 4; ++nt) {
    int pxl = nt * 16 + l15;
    int chr = (l4 & 1) ^ (pxl & 1);   // l4>=2 rereads: any data x Gpad-zeros = 0
    short8 Bf = *(const short8*)(&Eb[wv * 1024 + pxl * 16 + chr * 8]);
    float mx = -3.0e38f;
#pragma unroll
    for (int m5 = 0; m5 < 5; ++m5) {
      f32x4 s = __builtin_amdgcn_mfma_f32_16x16x32_bf16(Ga[m5], Bf, zf, 0, 0, 0);
#pragma unroll
      for (int rr = 0; rr < 4; ++rr) mx = fmaxf(mx, s[rr] + cst[m5][rr]);
    }
    mx = fmaxf(mx, __shfl_xor(mx, 16));
    mx = fmaxf(mx, __shfl_xor(mx, 32));
    if (lane < 16) AWLf[wv * 64 + nt * 16 + lane] = 1.f / (1.f + __expf(-(mx * 0.25f + bias)));
  }

  // epilogue: BN + gate + store (wave-private AWL)
  float s2v[2], t2v[2];
#pragma unroll
  for (int nt = 0; nt < 2; ++nt) {
    int co = blkN * 64 + nh * 32 + nt * 16 + l15;
    s2v[nt] = s2[co];
    t2v[nt] = t2[co];
  }
#pragma unroll
  for (int j = 0; j < 4; ++j) {
    int h = h0 + mh * 2 + (j >> 1);
    int wbase = w0 + (j & 1) * 16 + l4 * 4;
    int pb = (j >> 1) * 32 + (j & 1) * 16 + l4 * 4;
    f32x4 a0 = *(const f32x4*)(&AWLf[wv * 64 + pb]);
#pragma unroll
    for (int nt = 0; nt < 2; ++nt) {
      int co = blkN * 64 + nh * 32 + nt * 16 + l15;
      f32x4 o;
#pragma unroll
      for (int rr = 0; rr < 4; ++rr) o[rr] = (acc[j][nt][rr] * s2v[nt] + t2v[nt]) * a0[rr];
      *(f32x4*)(out + (size_t)(b * 128 + co) * 25600 + h * 160 + wbase) = o;
    }
  }
}

// ------------------------------------------------------------------
extern "C" void kernel_launch(void* const* d_in, const int* in_sizes, int n_in,
                              void* d_out, int out_size, void* d_ws, size_t ws_size,
                              hipStream_t stream) {
  (void)in_sizes; (void)n_in; (void)out_size; (void)ws_size;
  const float* x         = (const float*)d_in[0];
  const float* guide     = (const float*)d_in[1];
  const float* w_embed   = (const float*)d_in[2];
  const float* g1        = (const float*)d_in[3];
  const float* b1        = (const float*)d_in[4];
  const float* rm1       = (const float*)d_in[5];
  const float* rv1       = (const float*)d_in[6];
  const float* Wg        = (const float*)d_in[7];
  const float* bg        = (const float*)d_in[8];
  const float* attn_bias = (const float*)d_in[9];
  const float* w_proj    = (const float*)d_in[10];
  const float* g2        = (const float*)d_in[11];
  const float* b2        = (const float*)d_in[12];
  const float* rm2       = (const float*)d_in[13];
  const float* rv2       = (const float*)d_in[14];
  float* out = (float*)d_out;

  char* ws = (char*)d_ws;
  unsigned short* P2   = (unsigned short*)(ws);               // 58,392,576 B
  unsigned short* W1t  = (unsigned short*)(ws + 58392576);    //     16,384 B
  unsigned short* Wpt  = (unsigned short*)(ws + 58408960);    //    294,912 B
  unsigned short* Gpad = (unsigned short*)(ws + 58703872);    //    163,840 B
  float* Cst           = (float*)(ws + 58867712);             //     10,240 B
  float* s2            = (float*)(ws + 58877952);             //        512 B
  float* t2            = (float*)(ws + 58878464);             //        512 B
  // total ws usage: 58,878,976 B

  k_prep_x<<<8 * 112, 256, 0, stream>>>(x, P2);
  k_prep_misc<<<609, 256, 0, stream>>>(w_embed, w_proj, g2, b2, rm2, rv2, W1t, Wpt, s2, t2);
  k_guide<<<640, 64, 0, stream>>>(guide, Wg, bg, g1, b1, rm1, rv1, Gpad, Cst);
  k_mega<<<3200, 256, 0, stream>>>(P2, W1t, Wpt, Gpad, Cst, attn_bias, s2, t2, out);
}